// Round 5
// baseline (589.138 us; speedup 1.0000x reference)
//
#include <hip/hip_runtime.h>
#include <cstddef>

#define DD 128
#define EPS 1e-5f

typedef short short8 __attribute__((ext_vector_type(8)));
typedef float float4v __attribute__((ext_vector_type(4)));

__device__ __forceinline__ unsigned short f2bf(float f) {
    union { float f; unsigned int u; } x; x.f = f;
    unsigned int r = x.u + 0x7fffu + ((x.u >> 16) & 1u);   // RNE
    return (unsigned short)(r >> 16);
}
__device__ __forceinline__ float bfhi2f(unsigned int hi_bits) {
    union { unsigned int u; float f; } x; x.u = hi_bits;
    return x.f;
}

// ---------------- CSR build (padded: each row to multiple of 4 slots) ------

__global__ void hist_kernel(const int* __restrict__ row, int* __restrict__ deg, int E) {
    int e = blockIdx.x * blockDim.x + threadIdx.x;
    if (e < E) atomicAdd(&deg[row[e]], 1);
}

// scans PADDED degree: pdeg = (deg+3) & ~3
__global__ void scanA_kernel(const int* __restrict__ deg, int* __restrict__ tmp,
                             int* __restrict__ bsum, int n) {
    __shared__ int s[1024];
    int tid = threadIdx.x;
    int gid = blockIdx.x * 1024 + tid;
    int v = (gid < n) ? ((deg[gid] + 3) & ~3) : 0;
    s[tid] = v;
    __syncthreads();
    for (int off = 1; off < 1024; off <<= 1) {
        int t = s[tid];
        int u = (tid >= off) ? s[tid - off] : 0;
        __syncthreads();
        s[tid] = t + u;
        __syncthreads();
    }
    if (gid < n) tmp[gid] = s[tid];
    if (tid == 1023) bsum[blockIdx.x] = s[1023];
}

__global__ void scanB_kernel(const int* __restrict__ bsum, int* __restrict__ boff,
                             int* __restrict__ row_start, int nb, int n) {
    __shared__ int s[128];
    int tid = threadIdx.x;
    int v = (tid < nb) ? bsum[tid] : 0;
    s[tid] = v;
    __syncthreads();
    for (int off = 1; off < 128; off <<= 1) {
        int t = s[tid];
        int u = (tid >= off) ? s[tid - off] : 0;
        __syncthreads();
        s[tid] = t + u;
        __syncthreads();
    }
    if (tid < nb) boff[tid] = s[tid] - v;
    if (tid == nb - 1) row_start[n] = s[tid];
}

// also initializes per-bucket cursors (bucket = 256 rows)
__global__ void scanC_kernel(const int* __restrict__ deg, const int* __restrict__ tmp,
                             const int* __restrict__ boff, int* __restrict__ row_start,
                             int* __restrict__ cursor, int* __restrict__ bcur, int n) {
    int gid = blockIdx.x * 1024 + threadIdx.x;
    if (gid < n) {
        int pd = (deg[gid] + 3) & ~3;
        int rs = tmp[gid] - pd + boff[blockIdx.x];
        row_start[gid] = rs;
        cursor[gid] = rs;
        if ((gid & 255) == 0) bcur[gid >> 8] = rs;
    }
}

// ---------------- reservation-based scatter ----------------
// Buckets of 256 rows. Phase 1: each block LDS-histograms its edge chunk,
// reserves one contiguous run per (block,bucket) with a single global
// atomicAdd (rotated bucket order), then writes each run as a private
// contiguous stretch -> full 64B lines, one XCD per line.
// r_local (8b) packed in bits 24-31 of the low word (col uses 17b).

__global__ __launch_bounds__(256) void scatter_phase1_kernel(
    const int* __restrict__ row, const int* __restrict__ col,
    const float* __restrict__ ew, int* __restrict__ bcur,
    unsigned long long* __restrict__ ebuf2, int E, int nbuck) {
    __shared__ int hist[512];
    __shared__ int cur[512];
    int tid = threadIdx.x;
    int b = blockIdx.x;
    int C = (E + gridDim.x - 1) / gridDim.x;
    int e0 = b * C, e1 = min(E, e0 + C);
    for (int t = tid; t < nbuck; t += 256) hist[t] = 0;
    __syncthreads();
    for (int e = e0 + tid; e < e1; e += 256)
        atomicAdd(&hist[row[e] >> 8], 1);
    __syncthreads();
    for (int i = tid; i < nbuck; i += 256) {
        int t = i + b * 37;
        t -= (t >= nbuck) ? nbuck * (t / nbuck) : 0;
        int h = hist[t];
        cur[t] = h ? atomicAdd(&bcur[t], h) : 0;
    }
    __syncthreads();
    for (int e = e0 + tid; e < e1; e += 256) {
        int r = row[e];
        int bk = r >> 8;
        int pos = atomicAdd(&cur[bk], 1);
        unsigned long long pk = (unsigned long long)((unsigned int)col[e]
                              | ((unsigned int)(r & 255) << 24))
                              | ((unsigned long long)__float_as_uint(ew[e]) << 32);
        ebuf2[pos] = pk;
    }
}

// Phase 2: one block per 256-row bucket. CSR-order within the bucket via
// per-row LDS cursors; pad slots zero-filled (col=0, w=0); then a fully-
// coalesced streaming write of the padded window.
#define P2CAP 6144

__global__ __launch_bounds__(256) void scatter_phase2_kernel(
    const unsigned long long* __restrict__ ebuf2, const int* __restrict__ row_start,
    const int* __restrict__ bcur_final, int* __restrict__ cursor,
    unsigned long long* __restrict__ ebuf, int N) {
    __shared__ int cur[256];
    __shared__ unsigned long long outb[P2CAP];
    int b = blockIdx.x;
    int r_lo = b << 8;
    int r_hi = min(N, r_lo + 256);
    int e_lo = row_start[r_lo];
    int e_hi = row_start[r_hi];
    int cnt_pad = e_hi - e_lo;
    int cnt_real = bcur_final[b] - e_lo;
    int tid = threadIdx.x;
    if (cnt_pad <= P2CAP) {
        int r = r_lo + tid;
        cur[tid] = (r < N) ? (row_start[r] - e_lo) : 0;
        for (int i = tid; i < cnt_pad; i += 256) outb[i] = 0ull;
        __syncthreads();
        for (int i = e_lo + tid; i < e_lo + cnt_real; i += 256) {
            unsigned long long pk = ebuf2[i];
            int rl = (int)((unsigned int)(pk >> 24) & 255u);
            int pos = atomicAdd(&cur[rl], 1);
            outb[pos] = pk & 0xFFFFFFFF0001FFFFull;
        }
        __syncthreads();
        for (int i = tid; i < cnt_pad; i += 256)
            ebuf[e_lo + i] = outb[i];
    } else {
        // overflow fallback (never expected): zero window then global scatter
        for (int i = e_lo + tid; i < e_hi; i += 256) ebuf[i] = 0ull;
        __threadfence();
        __syncthreads();
        for (int i = e_lo + tid; i < e_lo + cnt_real; i += 256) {
            unsigned long long pk = ebuf2[i];
            int rl = (int)((unsigned int)(pk >> 24) & 255u);
            int pos = atomicAdd(&cursor[r_lo + rl], 1);
            ebuf[pos] = pk & 0xFFFFFFFF0001FFFFull;
        }
    }
}

// ---------------- W -> W^T bf16 ----------------

__global__ void convw_kernel(const float* __restrict__ W0, const float* __restrict__ W1,
                             const float* __restrict__ W2, unsigned short* __restrict__ T0,
                             unsigned short* __restrict__ T1, unsigned short* __restrict__ T2) {
    const float* W = (blockIdx.y == 0) ? W0 : (blockIdx.y == 1) ? W1 : W2;
    unsigned short* T = (blockIdx.y == 0) ? T0 : (blockIdx.y == 1) ? T1 : T2;
    int gid = blockIdx.x * 256 + threadIdx.x;
    int k = gid >> 7, n = gid & 127;
    T[n * DD + k] = f2bf(W[k * DD + n]);
}

// ---------------- MFMA GEMM (layer 0): H_bf16 = A_fp32 @ W + b ----------------
// A-fragments loaded DIRECTLY from global (each lane's 32B chunk; per-instr
// 16 full 64B lines, fully consumed). LDS only for W tile + C epilogue.

__global__ __launch_bounds__(256) void gemm_mfma_f32_kernel(
    const float* __restrict__ A, const unsigned short* __restrict__ Wt,
    const float* __restrict__ bias, unsigned short* __restrict__ H, int nrows)
{
    __shared__ unsigned short Asl[64][136];
    __shared__ unsigned short Wsl[128][136];

    const int tid  = threadIdx.x;
    const int row0 = blockIdx.x * 64;

    for (int i = tid; i < 2048; i += 256) {
        int r = i >> 4, off = (i & 15) * 8;
        *(uint4*)&Wsl[r][off] = *(const uint4*)(Wt + (size_t)r * DD + off);
    }
    __syncthreads();

    const int w = tid >> 6, lane = tid & 63;
    const int m = lane & 15, q = lane >> 4;
    const int grow = row0 + w * 16 + m;
    const bool inb = grow < nrows;

    short8 afr[4];
    #pragma unroll
    for (int c = 0; c < 4; ++c) {
        float4 v0 = make_float4(0.f, 0.f, 0.f, 0.f);
        float4 v1 = v0;
        if (inb) {
            v0 = *(const float4*)(A + (size_t)grow * DD + c * 32 + q * 8);
            v1 = *(const float4*)(A + (size_t)grow * DD + c * 32 + q * 8 + 4);
        }
        short8 t;
        t[0] = (short)f2bf(v0.x); t[1] = (short)f2bf(v0.y);
        t[2] = (short)f2bf(v0.z); t[3] = (short)f2bf(v0.w);
        t[4] = (short)f2bf(v1.x); t[5] = (short)f2bf(v1.y);
        t[6] = (short)f2bf(v1.z); t[7] = (short)f2bf(v1.w);
        afr[c] = t;
    }

    float4v acc[8];
    #pragma unroll
    for (int t = 0; t < 8; ++t) acc[t] = (float4v){0.f, 0.f, 0.f, 0.f};

    #pragma unroll
    for (int t = 0; t < 8; ++t) {
        #pragma unroll
        for (int c = 0; c < 4; ++c) {
            short8 bfr = *(const short8*)&Wsl[t * 16 + m][c * 32 + q * 8];
            acc[t] = __builtin_amdgcn_mfma_f32_16x16x32_bf16(afr[c], bfr, acc[t], 0, 0, 0);
        }
    }

    #pragma unroll
    for (int t = 0; t < 8; ++t) {
        float bv = bias[t * 16 + m];
        #pragma unroll
        for (int i = 0; i < 4; ++i)
            Asl[w * 16 + q * 4 + i][t * 16 + m] = f2bf(acc[t][i] + bv);
    }
    __syncthreads();

    for (int i = tid; i < 1024; i += 256) {
        int r = i >> 4, off = (i & 15) * 8;
        if (row0 + r < nrows)
            *(uint4*)(H + (size_t)(row0 + r) * DD + off) = *(const uint4*)&Asl[r][off];
    }
}

// ---------------- MFMA GEMM (layers 1/2): H_bf16 = relu(bn(A_bf16)) @ W + b --
// BN finalize fused; A-fragments direct from global, BN+ReLU in-register.

__global__ __launch_bounds__(256) void gemm_mfma_bf16_kernel(
    const unsigned int* __restrict__ A, const unsigned short* __restrict__ Wt,
    const float* __restrict__ bias,
    const float* __restrict__ sums, const float* __restrict__ g,
    const float* __restrict__ be,
    unsigned short* __restrict__ H, int nrows)
{
    __shared__ unsigned short Asl[64][136];
    __shared__ unsigned short Wsl[128][136];
    __shared__ float scl_s[128], sft_s[128];

    const int tid  = threadIdx.x;
    const int row0 = blockIdx.x * 64;

    if (tid < 128) {
        float inv_n = 1.0f / (float)nrows;
        float mean = sums[tid] * inv_n;
        float var = sums[128 + tid] * inv_n - mean * mean;
        float rstd = rsqrtf(var + EPS);
        float sc = g[tid] * rstd;
        scl_s[tid] = sc;
        sft_s[tid] = be[tid] - mean * sc;
    }

    for (int i = tid; i < 2048; i += 256) {
        int r = i >> 4, off = (i & 15) * 8;
        *(uint4*)&Wsl[r][off] = *(const uint4*)(Wt + (size_t)r * DD + off);
    }
    __syncthreads();

    const int w = tid >> 6, lane = tid & 63;
    const int m = lane & 15, q = lane >> 4;
    const int grow = row0 + w * 16 + m;
    const bool inb = grow < nrows;

    short8 afr[4];
    #pragma unroll
    for (int c = 0; c < 4; ++c) {
        uint4 ua = make_uint4(0, 0, 0, 0);
        if (inb)
            ua = *(const uint4*)(A + (size_t)grow * 64 + c * 16 + q * 4);
        unsigned int uu[4] = {ua.x, ua.y, ua.z, ua.w};
        short8 t;
        #pragma unroll
        for (int j = 0; j < 4; ++j) {
            int k = c * 32 + q * 8 + 2 * j;
            float vx = fmaxf(0.f, bfhi2f(uu[j] << 16) * scl_s[k] + sft_s[k]);
            float vy = fmaxf(0.f, bfhi2f(uu[j] & 0xffff0000u) * scl_s[k + 1] + sft_s[k + 1]);
            t[2 * j]     = (short)f2bf(vx);
            t[2 * j + 1] = (short)f2bf(vy);
        }
        afr[c] = t;
    }

    float4v acc[8];
    #pragma unroll
    for (int t = 0; t < 8; ++t) acc[t] = (float4v){0.f, 0.f, 0.f, 0.f};

    #pragma unroll
    for (int t = 0; t < 8; ++t) {
        #pragma unroll
        for (int c = 0; c < 4; ++c) {
            short8 bfr = *(const short8*)&Wsl[t * 16 + m][c * 32 + q * 8];
            acc[t] = __builtin_amdgcn_mfma_f32_16x16x32_bf16(afr[c], bfr, acc[t], 0, 0, 0);
        }
    }

    #pragma unroll
    for (int t = 0; t < 8; ++t) {
        float bv = bias[t * 16 + m];
        #pragma unroll
        for (int i = 0; i < 4; ++i)
            Asl[w * 16 + q * 4 + i][t * 16 + m] = f2bf(acc[t][i] + bv);
    }
    __syncthreads();

    for (int i = tid; i < 1024; i += 256) {
        int r = i >> 4, off = (i & 15) * 8;
        if (row0 + r < nrows)
            *(uint4*)(H + (size_t)(row0 + r) * DD + off) = *(const uint4*)&Asl[r][off];
    }
}

// ---------------- SpMM v4: S = A_csr @ H_bf16 (+fused BN partial stats) ----
// Padded CSR (rows = multiples of 4 slots; pad col=0,w=0) -> no tail. 2-stage
// pipeline per 4-edge group. When pbuf!=null, per-block channel sum/sumsq
// partials (of the bf16-ROUNDED outputs) are LDS-reduced and written to
// pbuf[block][256] for a tiny follow-up reduction.

__global__ __launch_bounds__(256, 8) void spmm_bf16_kernel(
    const unsigned short* __restrict__ H, const int* __restrict__ ps,
    const unsigned long long* __restrict__ ebuf,
    float* __restrict__ Sf, unsigned int* __restrict__ Sb, int writeBF,
    float* __restrict__ pbuf, int N, int K)
{
    __shared__ float sred[1024];   // [part:2][wave:4][ch:128]

    const int tid  = threadIdx.x;
    const int lane = tid & 63;
    const int g = lane >> 4;        // edge slot within a 4-edge group
    const int p = lane & 15;        // 16B chunk: channels p*8 .. p*8+7
    const int wv = tid >> 6;
    const int wave = (blockIdx.x << 2) | wv;
    const int r0 = wave * K;
    const bool active = (r0 < N);

    float st_s[8], st_q[8];
    #pragma unroll
    for (int j = 0; j < 8; ++j) { st_s[j] = 0.f; st_q[j] = 0.f; }

    if (active) {
        const int r1 = min(N, r0 + K);
        const unsigned short* Hp = H + p * 8;

        int r = r0;
        int e = ps[r0];
        const int eEnd = ps[r1];

        // leading zero-degree rows
        while (r < r1 && ps[r + 1] == e) {
            if (g == 0) {
                if (writeBF) {
                    uint4 z = make_uint4(0, 0, 0, 0);
                    *(uint4*)(Sb + (size_t)r * 64 + p * 4) = z;
                } else {
                    float4 z = make_float4(0.f, 0.f, 0.f, 0.f);
                    *(float4*)(Sf + (size_t)r * DD + p * 8) = z;
                    *(float4*)(Sf + (size_t)r * DD + p * 8 + 4) = z;
                }
            }
            ++r;
        }

        if (r < r1) {
            int next_end = ps[r + 1];

            unsigned long long pk_cur = __builtin_nontemporal_load(&ebuf[e + g]);
            int i1 = e + 4; i1 = (i1 < eEnd) ? i1 : e;
            unsigned long long pk_nxt = __builtin_nontemporal_load(&ebuf[i1 + g]);
            uint4 u_cur = *(const uint4*)(Hp + (size_t)(unsigned int)pk_cur * DD);

            float acc[8];
            #pragma unroll
            for (int j = 0; j < 8; ++j) acc[j] = 0.f;

            for (; e < eEnd; e += 4) {
                int i2 = e + 8; i2 = (i2 < eEnd) ? i2 : e;
                unsigned long long pk_f = __builtin_nontemporal_load(&ebuf[i2 + g]);
                uint4 u_nxt = *(const uint4*)(Hp + (size_t)(unsigned int)pk_nxt * DD);
                float wj = __uint_as_float((unsigned int)(pk_cur >> 32));
                unsigned int uu[4] = {u_cur.x, u_cur.y, u_cur.z, u_cur.w};
                #pragma unroll
                for (int q4 = 0; q4 < 4; ++q4) {
                    acc[2 * q4]     += wj * bfhi2f(uu[q4] << 16);
                    acc[2 * q4 + 1] += wj * bfhi2f(uu[q4] & 0xffff0000u);
                }

                while (e + 4 == next_end) {
                    #pragma unroll
                    for (int j = 0; j < 8; ++j) {
                        acc[j] += __shfl_xor(acc[j], 16);
                        acc[j] += __shfl_xor(acc[j], 32);
                    }
                    if (g == 0) {
                        if (writeBF) {
                            unsigned int o[4];
                            #pragma unroll
                            for (int j = 0; j < 4; ++j)
                                o[j] = (unsigned int)f2bf(acc[2 * j])
                                     | ((unsigned int)f2bf(acc[2 * j + 1]) << 16);
                            *(uint4*)(Sb + (size_t)r * 64 + p * 4) = *(const uint4*)o;
                            if (pbuf) {
                                #pragma unroll
                                for (int j = 0; j < 4; ++j) {
                                    float vx = bfhi2f(o[j] << 16);
                                    float vy = bfhi2f(o[j] & 0xffff0000u);
                                    st_s[2 * j] += vx; st_q[2 * j] += vx * vx;
                                    st_s[2 * j + 1] += vy; st_q[2 * j + 1] += vy * vy;
                                }
                            }
                        } else {
                            float4 lo = make_float4(acc[0], acc[1], acc[2], acc[3]);
                            float4 hi = make_float4(acc[4], acc[5], acc[6], acc[7]);
                            *(float4*)(Sf + (size_t)r * DD + p * 8) = lo;
                            *(float4*)(Sf + (size_t)r * DD + p * 8 + 4) = hi;
                        }
                    }
                    #pragma unroll
                    for (int j = 0; j < 8; ++j) acc[j] = 0.f;
                    ++r;
                    if (r >= r1) break;
                    next_end = ps[r + 1];
                }

                pk_cur = pk_nxt;
                u_cur  = u_nxt;
                pk_nxt = pk_f;
            }
        }
    }

    // ---- per-block stats reduction (uniform branch; all waves participate)
    if (pbuf) {
        for (int i = tid; i < 1024; i += 256) sred[i] = 0.f;
        __syncthreads();
        if (active && g == 0) {
            #pragma unroll
            for (int k = 0; k < 8; ++k) {
                sred[wv * 128 + p * 8 + k]       = st_s[k];
                sred[512 + wv * 128 + p * 8 + k] = st_q[k];
            }
        }
        __syncthreads();
        {
            int part = tid >> 7, ch = tid & 127;
            int base = part * 512 + ch;
            float v = sred[base] + sred[base + 128] + sred[base + 256] + sred[base + 384];
            pbuf[(size_t)blockIdx.x * 256 + tid] = v;
        }
    }
}

// ---------------- BN stats final reduce: sums[256] += column-sums of pbuf ---

__global__ __launch_bounds__(256) void bn_reduce_kernel(
    const float* __restrict__ pbuf, float* __restrict__ sums, int nb) {
    int c = threadIdx.x;
    float s = 0.f;
    for (int b = blockIdx.x; b < nb; b += gridDim.x)
        s += pbuf[(size_t)b * 256 + c];
    atomicAdd(&sums[c], s);
}

// ---------------- launch ----------------

extern "C" void kernel_launch(void* const* d_in, const int* in_sizes, int n_in,
                              void* d_out, int out_size, void* d_ws, size_t ws_size,
                              hipStream_t stream) {
    const float* x   = (const float*)d_in[0];
    const float* ew  = (const float*)d_in[1];
    const float* W0  = (const float*)d_in[2];
    const float* b0  = (const float*)d_in[3];
    const float* g0  = (const float*)d_in[4];
    const float* be0 = (const float*)d_in[5];
    const float* W1  = (const float*)d_in[6];
    const float* b1  = (const float*)d_in[7];
    const float* g1  = (const float*)d_in[8];
    const float* be1 = (const float*)d_in[9];
    const float* W2  = (const float*)d_in[10];
    const float* b2  = (const float*)d_in[11];
    const int* row   = (const int*)d_in[12];
    const int* col   = (const int*)d_in[13];

    const int N = in_sizes[0] / DD;
    const int E = in_sizes[1];
    float* out = (float*)d_out;

    const int SPMM_BLOCKS = 4096;

    // padded edge capacity: sum(ceil(deg/4)*4) <= E + 3N
    const size_t EPADCAP = (size_t)E + 3 * (size_t)N + 64;

    char* w = (char*)d_ws;
    unsigned short* H   = (unsigned short*)w; w += (size_t)N * DD * 2;
    unsigned int* Sb    = (unsigned int*)w;   w += (size_t)N * 64 * 4;
    unsigned long long* ebuf = (unsigned long long*)w; w += EPADCAP * 8;
    float* pbuf         = (float*)w;          w += (size_t)SPMM_BLOCKS * 256 * 4;
    unsigned short* Wt0 = (unsigned short*)w; w += DD * DD * 2;
    unsigned short* Wt1 = (unsigned short*)w; w += DD * DD * 2;
    unsigned short* Wt2 = (unsigned short*)w; w += DD * DD * 2;
    float* sums         = (float*)w;          w += 256 * 4;
    int*   deg          = (int*)w;            w += (size_t)N * 4;
    int*   tmp          = (int*)w;            w += (size_t)N * 4;
    int*   cursor       = (int*)w;            w += (size_t)N * 4;
    int*   bsum         = (int*)w;            w += 128 * 4;
    int*   boff         = (int*)w;            w += 128 * 4;
    int*   row_start    = (int*)w;            w += (size_t)(N + 1) * 4;

    // staging for phase-1 scatter reuses Sb (free until spmm layer 0);
    // per-bucket cursors reuse tmp (free after scanC)
    unsigned long long* ebuf2 = (unsigned long long*)Sb;
    int* bcur = tmp;
    int nbuck = (N + 255) >> 8;   // 256 rows per bucket, <= 512 buckets

    // ---- padded CSR build (reused by all 3 SpMMs) ----
    hipMemsetAsync(deg, 0, (size_t)N * 4, stream);
    hist_kernel<<<(E + 255) / 256, 256, 0, stream>>>(row, deg, E);
    int NB = (N + 1023) / 1024;
    scanA_kernel<<<NB, 1024, 0, stream>>>(deg, tmp, bsum, N);
    scanB_kernel<<<1, 128, 0, stream>>>(bsum, boff, row_start, NB, N);
    scanC_kernel<<<NB, 1024, 0, stream>>>(deg, tmp, boff, row_start, cursor, bcur, N);
    scatter_phase1_kernel<<<256, 256, 0, stream>>>(row, col, ew, bcur, ebuf2, E, nbuck);
    scatter_phase2_kernel<<<nbuck, 256, 0, stream>>>(ebuf2, row_start, bcur, cursor, ebuf, N);

    convw_kernel<<<dim3(64, 3), 256, 0, stream>>>(W0, W1, W2, Wt0, Wt1, Wt2);

    int gblocks = (N + 63) / 64;

    const int totalWaves = SPMM_BLOCKS * 4;
    const int K = (N + totalWaves - 1) / totalWaves;

    // ---- layer 0 ----
    gemm_mfma_f32_kernel<<<gblocks, 256, 0, stream>>>(x, Wt0, b0, H, N);
    hipMemsetAsync(sums, 0, 256 * 4, stream);
    spmm_bf16_kernel<<<SPMM_BLOCKS, 256, 0, stream>>>(H, row_start, ebuf, nullptr, Sb, 1, pbuf, N, K);
    bn_reduce_kernel<<<64, 256, 0, stream>>>(pbuf, sums, SPMM_BLOCKS);

    // ---- layer 1 ----
    gemm_mfma_bf16_kernel<<<gblocks, 256, 0, stream>>>(Sb, Wt1, b1, sums, g0, be0, H, N);
    hipMemsetAsync(sums, 0, 256 * 4, stream);
    spmm_bf16_kernel<<<SPMM_BLOCKS, 256, 0, stream>>>(H, row_start, ebuf, nullptr, Sb, 1, pbuf, N, K);
    bn_reduce_kernel<<<64, 256, 0, stream>>>(pbuf, sums, SPMM_BLOCKS);

    // ---- layer 2 (final: fp32 out, no BN after) ----
    gemm_mfma_bf16_kernel<<<gblocks, 256, 0, stream>>>(Sb, Wt2, b2, sums, g1, be1, H, N);
    spmm_bf16_kernel<<<SPMM_BLOCKS, 256, 0, stream>>>(H, row_start, ebuf, out, nullptr, 0, nullptr, N, K);
}

// Round 6
// 567.245 us; speedup vs baseline: 1.0386x; 1.0386x over previous
//
#include <hip/hip_runtime.h>
#include <cstddef>

#define DD 128
#define EPS 1e-5f

typedef short short8 __attribute__((ext_vector_type(8)));
typedef float float4v __attribute__((ext_vector_type(4)));

__device__ __forceinline__ unsigned short f2bf(float f) {
    union { float f; unsigned int u; } x; x.f = f;
    unsigned int r = x.u + 0x7fffu + ((x.u >> 16) & 1u);   // RNE
    return (unsigned short)(r >> 16);
}
__device__ __forceinline__ float bfhi2f(unsigned int hi_bits) {
    union { unsigned int u; float f; } x; x.u = hi_bits;
    return x.f;
}

// ---------------- CSR build ----------------

__global__ void hist_kernel(const int* __restrict__ row, int* __restrict__ deg, int E) {
    int e = blockIdx.x * blockDim.x + threadIdx.x;
    if (e < E) atomicAdd(&deg[row[e]], 1);
}

__global__ void scanA_kernel(const int* __restrict__ deg, int* __restrict__ tmp,
                             int* __restrict__ bsum, int n) {
    __shared__ int s[1024];
    int tid = threadIdx.x;
    int gid = blockIdx.x * 1024 + tid;
    int v = (gid < n) ? deg[gid] : 0;
    s[tid] = v;
    __syncthreads();
    for (int off = 1; off < 1024; off <<= 1) {
        int t = s[tid];
        int u = (tid >= off) ? s[tid - off] : 0;
        __syncthreads();
        s[tid] = t + u;
        __syncthreads();
    }
    if (gid < n) tmp[gid] = s[tid];
    if (tid == 1023) bsum[blockIdx.x] = s[1023];
}

__global__ void scanB_kernel(const int* __restrict__ bsum, int* __restrict__ boff,
                             int* __restrict__ row_start, int nb, int n) {
    __shared__ int s[128];
    int tid = threadIdx.x;
    int v = (tid < nb) ? bsum[tid] : 0;
    s[tid] = v;
    __syncthreads();
    for (int off = 1; off < 128; off <<= 1) {
        int t = s[tid];
        int u = (tid >= off) ? s[tid - off] : 0;
        __syncthreads();
        s[tid] = t + u;
        __syncthreads();
    }
    if (tid < nb) boff[tid] = s[tid] - v;
    if (tid == nb - 1) row_start[n] = s[tid];
}

// also initializes per-bucket cursors (bucket = 256 rows)
__global__ void scanC_kernel(const int* __restrict__ deg, const int* __restrict__ tmp,
                             const int* __restrict__ boff, int* __restrict__ row_start,
                             int* __restrict__ cursor, int* __restrict__ bcur, int n) {
    int gid = blockIdx.x * 1024 + threadIdx.x;
    if (gid < n) {
        int rs = tmp[gid] - deg[gid] + boff[blockIdx.x];
        row_start[gid] = rs;
        cursor[gid] = rs;
        if ((gid & 255) == 0) bcur[gid >> 8] = rs;
    }
}

// ---------------- reservation-based scatter ----------------
// Buckets of 256 rows. Phase 1: each block LDS-histograms its edge chunk,
// reserves one contiguous run per (block,bucket) with a single global
// atomicAdd (rotated bucket order), then writes each run as a private
// contiguous stretch -> full 64B lines, one XCD per line.
// r_local (8b) packed in bits 24-31 of the low word (col uses 17b).

__global__ __launch_bounds__(256) void scatter_phase1_kernel(
    const int* __restrict__ row, const int* __restrict__ col,
    const float* __restrict__ ew, int* __restrict__ bcur,
    unsigned long long* __restrict__ ebuf2, int E, int nbuck) {
    __shared__ int hist[512];
    __shared__ int cur[512];
    int tid = threadIdx.x;
    int b = blockIdx.x;
    int C = (E + gridDim.x - 1) / gridDim.x;
    int e0 = b * C, e1 = min(E, e0 + C);
    for (int t = tid; t < nbuck; t += 256) hist[t] = 0;
    __syncthreads();
    for (int e = e0 + tid; e < e1; e += 256)
        atomicAdd(&hist[row[e] >> 8], 1);
    __syncthreads();
    for (int i = tid; i < nbuck; i += 256) {
        int t = i + b * 37;
        t -= (t >= nbuck) ? nbuck * (t / nbuck) : 0;
        int h = hist[t];
        cur[t] = h ? atomicAdd(&bcur[t], h) : 0;
    }
    __syncthreads();
    for (int e = e0 + tid; e < e1; e += 256) {
        int r = row[e];
        int bk = r >> 8;
        int pos = atomicAdd(&cur[bk], 1);
        unsigned long long pk = (unsigned long long)((unsigned int)col[e]
                              | ((unsigned int)(r & 255) << 24))
                              | ((unsigned long long)__float_as_uint(ew[e]) << 32);
        ebuf2[pos] = pk;
    }
}

// Phase 2: one block per 256-row bucket. CSR-order within the bucket via
// per-row LDS cursors, then a fully-coalesced streaming write of the window.
#define P2CAP 6144

__global__ __launch_bounds__(256) void scatter_phase2_kernel(
    const unsigned long long* __restrict__ ebuf2, const int* __restrict__ row_start,
    int* __restrict__ cursor, unsigned long long* __restrict__ ebuf, int N) {
    __shared__ int cur[256];
    __shared__ unsigned long long outb[P2CAP];
    int b = blockIdx.x;
    int r_lo = b << 8;
    int r_hi = min(N, r_lo + 256);
    int e_lo = row_start[r_lo];
    int e_hi = row_start[r_hi];
    int cnt = e_hi - e_lo;
    int tid = threadIdx.x;
    if (cnt <= P2CAP) {
        int r = r_lo + tid;
        cur[tid] = (r < N) ? (row_start[r] - e_lo) : 0;
        __syncthreads();
        for (int i = e_lo + tid; i < e_hi; i += 256) {
            unsigned long long pk = ebuf2[i];
            int rl = (int)((unsigned int)(pk >> 24) & 255u);
            int pos = atomicAdd(&cur[rl], 1);
            outb[pos] = pk & 0xFFFFFFFF0001FFFFull;
        }
        __syncthreads();
        for (int i = tid; i < cnt; i += 256)
            ebuf[e_lo + i] = outb[i];
    } else {
        // overflow fallback (cap = mean + ~25 sigma; never expected):
        // direct global scatter via per-row cursors.
        for (int i = e_lo + tid; i < e_hi; i += 256) {
            unsigned long long pk = ebuf2[i];
            int rl = (int)((unsigned int)(pk >> 24) & 255u);
            int pos = atomicAdd(&cursor[r_lo + rl], 1);
            ebuf[pos] = pk & 0xFFFFFFFF0001FFFFull;
        }
    }
}

// ---------------- W -> W^T bf16 ----------------

__global__ void convw_kernel(const float* __restrict__ W0, const float* __restrict__ W1,
                             const float* __restrict__ W2, unsigned short* __restrict__ T0,
                             unsigned short* __restrict__ T1, unsigned short* __restrict__ T2) {
    const float* W = (blockIdx.y == 0) ? W0 : (blockIdx.y == 1) ? W1 : W2;
    unsigned short* T = (blockIdx.y == 0) ? T0 : (blockIdx.y == 1) ? T1 : T2;
    int gid = blockIdx.x * 256 + threadIdx.x;
    int k = gid >> 7, n = gid & 127;
    T[n * DD + k] = f2bf(W[k * DD + n]);
}

// ---------------- MFMA GEMM (layer 0): H_bf16 = A_fp32 @ W + b ----------------
// A-fragments loaded DIRECTLY from global (each lane's 32B chunk; per-instr
// 16 full 64B lines, fully consumed). LDS only for W tile + C epilogue.

__global__ __launch_bounds__(256) void gemm_mfma_f32_kernel(
    const float* __restrict__ A, const unsigned short* __restrict__ Wt,
    const float* __restrict__ bias, unsigned short* __restrict__ H, int nrows)
{
    __shared__ unsigned short Asl[64][136];
    __shared__ unsigned short Wsl[128][136];

    const int tid  = threadIdx.x;
    const int row0 = blockIdx.x * 64;

    for (int i = tid; i < 2048; i += 256) {
        int r = i >> 4, off = (i & 15) * 8;
        *(uint4*)&Wsl[r][off] = *(const uint4*)(Wt + (size_t)r * DD + off);
    }
    __syncthreads();

    const int w = tid >> 6, lane = tid & 63;
    const int m = lane & 15, q = lane >> 4;
    const int grow = row0 + w * 16 + m;
    const bool inb = grow < nrows;

    short8 afr[4];
    #pragma unroll
    for (int c = 0; c < 4; ++c) {
        float4 v0 = make_float4(0.f, 0.f, 0.f, 0.f);
        float4 v1 = v0;
        if (inb) {
            v0 = *(const float4*)(A + (size_t)grow * DD + c * 32 + q * 8);
            v1 = *(const float4*)(A + (size_t)grow * DD + c * 32 + q * 8 + 4);
        }
        short8 t;
        t[0] = (short)f2bf(v0.x); t[1] = (short)f2bf(v0.y);
        t[2] = (short)f2bf(v0.z); t[3] = (short)f2bf(v0.w);
        t[4] = (short)f2bf(v1.x); t[5] = (short)f2bf(v1.y);
        t[6] = (short)f2bf(v1.z); t[7] = (short)f2bf(v1.w);
        afr[c] = t;
    }

    float4v acc[8];
    #pragma unroll
    for (int t = 0; t < 8; ++t) acc[t] = (float4v){0.f, 0.f, 0.f, 0.f};

    #pragma unroll
    for (int t = 0; t < 8; ++t) {
        #pragma unroll
        for (int c = 0; c < 4; ++c) {
            short8 bfr = *(const short8*)&Wsl[t * 16 + m][c * 32 + q * 8];
            acc[t] = __builtin_amdgcn_mfma_f32_16x16x32_bf16(afr[c], bfr, acc[t], 0, 0, 0);
        }
    }

    #pragma unroll
    for (int t = 0; t < 8; ++t) {
        float bv = bias[t * 16 + m];
        #pragma unroll
        for (int i = 0; i < 4; ++i)
            Asl[w * 16 + q * 4 + i][t * 16 + m] = f2bf(acc[t][i] + bv);
    }
    __syncthreads();

    for (int i = tid; i < 1024; i += 256) {
        int r = i >> 4, off = (i & 15) * 8;
        if (row0 + r < nrows)
            *(uint4*)(H + (size_t)(row0 + r) * DD + off) = *(const uint4*)&Asl[r][off];
    }
}

// ---------------- MFMA GEMM (layers 1/2): H_bf16 = relu(bn(A_bf16)) @ W + b --
// BN finalize fused; A-fragments direct from global, BN+ReLU in-register.

__global__ __launch_bounds__(256) void gemm_mfma_bf16_kernel(
    const unsigned int* __restrict__ A, const unsigned short* __restrict__ Wt,
    const float* __restrict__ bias,
    const float* __restrict__ sums, const float* __restrict__ g,
    const float* __restrict__ be,
    unsigned short* __restrict__ H, int nrows)
{
    __shared__ unsigned short Asl[64][136];
    __shared__ unsigned short Wsl[128][136];
    __shared__ float scl_s[128], sft_s[128];

    const int tid  = threadIdx.x;
    const int row0 = blockIdx.x * 64;

    if (tid < 128) {
        float inv_n = 1.0f / (float)nrows;
        float mean = sums[tid] * inv_n;
        float var = sums[128 + tid] * inv_n - mean * mean;
        float rstd = rsqrtf(var + EPS);
        float sc = g[tid] * rstd;
        scl_s[tid] = sc;
        sft_s[tid] = be[tid] - mean * sc;
    }

    for (int i = tid; i < 2048; i += 256) {
        int r = i >> 4, off = (i & 15) * 8;
        *(uint4*)&Wsl[r][off] = *(const uint4*)(Wt + (size_t)r * DD + off);
    }
    __syncthreads();

    const int w = tid >> 6, lane = tid & 63;
    const int m = lane & 15, q = lane >> 4;
    const int grow = row0 + w * 16 + m;
    const bool inb = grow < nrows;

    short8 afr[4];
    #pragma unroll
    for (int c = 0; c < 4; ++c) {
        uint4 ua = make_uint4(0, 0, 0, 0);
        if (inb)
            ua = *(const uint4*)(A + (size_t)grow * 64 + c * 16 + q * 4);
        unsigned int uu[4] = {ua.x, ua.y, ua.z, ua.w};
        short8 t;
        #pragma unroll
        for (int j = 0; j < 4; ++j) {
            int k = c * 32 + q * 8 + 2 * j;
            float vx = fmaxf(0.f, bfhi2f(uu[j] << 16) * scl_s[k] + sft_s[k]);
            float vy = fmaxf(0.f, bfhi2f(uu[j] & 0xffff0000u) * scl_s[k + 1] + sft_s[k + 1]);
            t[2 * j]     = (short)f2bf(vx);
            t[2 * j + 1] = (short)f2bf(vy);
        }
        afr[c] = t;
    }

    float4v acc[8];
    #pragma unroll
    for (int t = 0; t < 8; ++t) acc[t] = (float4v){0.f, 0.f, 0.f, 0.f};

    #pragma unroll
    for (int t = 0; t < 8; ++t) {
        #pragma unroll
        for (int c = 0; c < 4; ++c) {
            short8 bfr = *(const short8*)&Wsl[t * 16 + m][c * 32 + q * 8];
            acc[t] = __builtin_amdgcn_mfma_f32_16x16x32_bf16(afr[c], bfr, acc[t], 0, 0, 0);
        }
    }

    #pragma unroll
    for (int t = 0; t < 8; ++t) {
        float bv = bias[t * 16 + m];
        #pragma unroll
        for (int i = 0; i < 4; ++i)
            Asl[w * 16 + q * 4 + i][t * 16 + m] = f2bf(acc[t][i] + bv);
    }
    __syncthreads();

    for (int i = tid; i < 1024; i += 256) {
        int r = i >> 4, off = (i & 15) * 8;
        if (row0 + r < nrows)
            *(uint4*)(H + (size_t)(row0 + r) * DD + off) = *(const uint4*)&Asl[r][off];
    }
}

// ---------------- SpMM: S = A_csr @ H_bf16 ----------------
// v2 (R3-verified): one wave per row-run; 4 edges per step (lane=[g:2][p:4]);
// each lane gathers 16B of one edge's H row -> 1KB per instr. Cross-slot
// reduce via shfl_xor(16/32). Grid-stride over contiguous row ranges.
// writeBF=1: S as packed bf16 pairs (layers 0/1); else fp32 (final).

__global__ __launch_bounds__(256, 8) void spmm_bf16_kernel(
    const unsigned short* __restrict__ H, const int* __restrict__ row_start,
    const unsigned long long* __restrict__ ebuf,
    float* __restrict__ Sf, unsigned int* __restrict__ Sb, int writeBF, int N, int K)
{
    const int lane = threadIdx.x & 63;
    const int g = lane >> 4;        // edge slot within a 4-edge batch
    const int p = lane & 15;        // 16B chunk: channels p*8 .. p*8+7
    const int wave = (blockIdx.x << 2) | (threadIdx.x >> 6);
    int r0 = wave * K;
    if (r0 >= N) return;
    int r1 = min(N, r0 + K);

    const unsigned short* Hp = H + p * 8;             // + col*DD per gather
    const unsigned long long* Ep = ebuf + g;

    for (int r = r0; r < r1; ++r) {
        int e = row_start[r];
        const int e1 = row_start[r + 1];
        float acc[8];
        #pragma unroll
        for (int j = 0; j < 8; ++j) acc[j] = 0.f;

        // 16 edges / iter: 4 batches, 4 gathers (4KB) in flight
        for (; e + 15 < e1; e += 16) {
            unsigned long long pk[4];
            #pragma unroll
            for (int j = 0; j < 4; ++j)
                pk[j] = __builtin_nontemporal_load(Ep + e + j * 4);
            uint4 u[4];
            #pragma unroll
            for (int j = 0; j < 4; ++j)
                u[j] = *(const uint4*)(Hp + (size_t)(unsigned int)pk[j] * DD);
            #pragma unroll
            for (int j = 0; j < 4; ++j) {
                float wj = __uint_as_float((unsigned int)(pk[j] >> 32));
                unsigned int uu[4] = {u[j].x, u[j].y, u[j].z, u[j].w};
                #pragma unroll
                for (int q = 0; q < 4; ++q) {
                    acc[2 * q]     += wj * bfhi2f(uu[q] << 16);
                    acc[2 * q + 1] += wj * bfhi2f(uu[q] & 0xffff0000u);
                }
            }
        }
        // 8 edges / iter: 2 batches
        for (; e + 7 < e1; e += 8) {
            unsigned long long pk[2];
            #pragma unroll
            for (int j = 0; j < 2; ++j)
                pk[j] = __builtin_nontemporal_load(Ep + e + j * 4);
            uint4 u[2];
            #pragma unroll
            for (int j = 0; j < 2; ++j)
                u[j] = *(const uint4*)(Hp + (size_t)(unsigned int)pk[j] * DD);
            #pragma unroll
            for (int j = 0; j < 2; ++j) {
                float wj = __uint_as_float((unsigned int)(pk[j] >> 32));
                unsigned int uu[4] = {u[j].x, u[j].y, u[j].z, u[j].w};
                #pragma unroll
                for (int q = 0; q < 4; ++q) {
                    acc[2 * q]     += wj * bfhi2f(uu[q] << 16);
                    acc[2 * q + 1] += wj * bfhi2f(uu[q] & 0xffff0000u);
                }
            }
        }
        // 4 edges
        if (e + 3 < e1) {
            unsigned long long pk = __builtin_nontemporal_load(Ep + e);
            uint4 u = *(const uint4*)(Hp + (size_t)(unsigned int)pk * DD);
            float wj = __uint_as_float((unsigned int)(pk >> 32));
            unsigned int uu[4] = {u.x, u.y, u.z, u.w};
            #pragma unroll
            for (int q = 0; q < 4; ++q) {
                acc[2 * q]     += wj * bfhi2f(uu[q] << 16);
                acc[2 * q + 1] += wj * bfhi2f(uu[q] & 0xffff0000u);
            }
            e += 4;
        }
        // tail 0..3 edges, branchless: inactive slots gather row 0 with w=0
        if (e < e1) {
            int idx = e + g;
            unsigned long long pk = (idx < e1) ? __builtin_nontemporal_load(&ebuf[idx]) : 0ull;
            uint4 u = *(const uint4*)(Hp + (size_t)(unsigned int)pk * DD);
            float wj = __uint_as_float((unsigned int)(pk >> 32));
            unsigned int uu[4] = {u.x, u.y, u.z, u.w};
            #pragma unroll
            for (int q = 0; q < 4; ++q) {
                acc[2 * q]     += wj * bfhi2f(uu[q] << 16);
                acc[2 * q + 1] += wj * bfhi2f(uu[q] & 0xffff0000u);
            }
        }

        // reduce across the 4 edge slots (lanes p, p+16, p+32, p+48)
        #pragma unroll
        for (int j = 0; j < 8; ++j) {
            acc[j] += __shfl_xor(acc[j], 16);
            acc[j] += __shfl_xor(acc[j], 32);
        }

        if (g == 0) {
            if (writeBF) {
                unsigned int o[4];
                #pragma unroll
                for (int j = 0; j < 4; ++j)
                    o[j] = (unsigned int)f2bf(acc[2 * j])
                         | ((unsigned int)f2bf(acc[2 * j + 1]) << 16);
                *(uint4*)(Sb + (size_t)r * 64 + p * 4) = *(const uint4*)o;
            } else {
                float4 lo = make_float4(acc[0], acc[1], acc[2], acc[3]);
                float4 hi = make_float4(acc[4], acc[5], acc[6], acc[7]);
                *(float4*)(Sf + (size_t)r * DD + p * 8) = lo;
                *(float4*)(Sf + (size_t)r * DD + p * 8 + 4) = hi;
            }
        }
    }
}

// ---------------- BatchNorm stats over bf16 S ----------------

__global__ void bn_stats_bf16_kernel(const unsigned int* __restrict__ Sb,
                                     float* __restrict__ sums, int n) {
    __shared__ float lsx[256], lsx2[256], lsy[256], lsy2[256];
    int tid = threadIdx.x;
    int c2 = tid & 63;      // pair index -> channels 2c2, 2c2+1
    float sx = 0.f, sx2 = 0.f, sy = 0.f, sy2 = 0.f;
    int total = n * 64;
    for (int i = blockIdx.x * 256 + tid; i < total; i += 256 * 256) {
        unsigned int u = Sb[i];
        float vx = bfhi2f(u << 16);
        float vy = bfhi2f(u & 0xffff0000u);
        sx += vx; sx2 += vx * vx;
        sy += vy; sy2 += vy * vy;
    }
    lsx[tid] = sx; lsx2[tid] = sx2; lsy[tid] = sy; lsy2[tid] = sy2;
    __syncthreads();
    if (tid < 64) {
        sx  = lsx[tid]  + lsx[tid + 64]  + lsx[tid + 128]  + lsx[tid + 192];
        sx2 = lsx2[tid] + lsx2[tid + 64] + lsx2[tid + 128] + lsx2[tid + 192];
        sy  = lsy[tid]  + lsy[tid + 64]  + lsy[tid + 128]  + lsy[tid + 192];
        sy2 = lsy2[tid] + lsy2[tid + 64] + lsy2[tid + 128] + lsy2[tid + 192];
        atomicAdd(&sums[2 * c2], sx);
        atomicAdd(&sums[2 * c2 + 1], sy);
        atomicAdd(&sums[128 + 2 * c2], sx2);
        atomicAdd(&sums[129 + 2 * c2], sy2);
    }
}

// ---------------- launch ----------------

extern "C" void kernel_launch(void* const* d_in, const int* in_sizes, int n_in,
                              void* d_out, int out_size, void* d_ws, size_t ws_size,
                              hipStream_t stream) {
    const float* x   = (const float*)d_in[0];
    const float* ew  = (const float*)d_in[1];
    const float* W0  = (const float*)d_in[2];
    const float* b0  = (const float*)d_in[3];
    const float* g0  = (const float*)d_in[4];
    const float* be0 = (const float*)d_in[5];
    const float* W1  = (const float*)d_in[6];
    const float* b1  = (const float*)d_in[7];
    const float* g1  = (const float*)d_in[8];
    const float* be1 = (const float*)d_in[9];
    const float* W2  = (const float*)d_in[10];
    const float* b2  = (const float*)d_in[11];
    const int* row   = (const int*)d_in[12];
    const int* col   = (const int*)d_in[13];

    const int N = in_sizes[0] / DD;
    const int E = in_sizes[1];
    float* out = (float*)d_out;

    char* w = (char*)d_ws;
    unsigned short* H   = (unsigned short*)w; w += (size_t)N * DD * 2;
    unsigned int* Sb    = (unsigned int*)w;   w += (size_t)N * 64 * 4;
    unsigned long long* ebuf = (unsigned long long*)w; w += (size_t)E * 8;
    unsigned short* Wt0 = (unsigned short*)w; w += DD * DD * 2;
    unsigned short* Wt1 = (unsigned short*)w; w += DD * DD * 2;
    unsigned short* Wt2 = (unsigned short*)w; w += DD * DD * 2;
    float* sums         = (float*)w;          w += 256 * 4;
    int*   deg          = (int*)w;            w += (size_t)N * 4;
    int*   tmp          = (int*)w;            w += (size_t)N * 4;
    int*   cursor       = (int*)w;            w += (size_t)N * 4;
    int*   bsum         = (int*)w;            w += 128 * 4;
    int*   boff         = (int*)w;            w += 128 * 4;
    int*   row_start    = (int*)w;            w += (size_t)(N + 1) * 4;

    // staging for phase-1 scatter reuses Sb (free until spmm layer 0);
    // per-bucket cursors reuse tmp (free after scanC)
    unsigned long long* ebuf2 = (unsigned long long*)Sb;
    int* bcur = tmp;
    int nbuck = (N + 255) >> 8;   // 256 rows per bucket, <= 512 buckets

    // ---- CSR build (reused by all 3 SpMMs) ----
    hipMemsetAsync(deg, 0, (size_t)N * 4, stream);
    hist_kernel<<<(E + 255) / 256, 256, 0, stream>>>(row, deg, E);
    int NB = (N + 1023) / 1024;
    scanA_kernel<<<NB, 1024, 0, stream>>>(deg, tmp, bsum, N);
    scanB_kernel<<<1, 128, 0, stream>>>(bsum, boff, row_start, NB, N);
    scanC_kernel<<<NB, 1024, 0, stream>>>(deg, tmp, boff, row_start, cursor, bcur, N);
    scatter_phase1_kernel<<<256, 256, 0, stream>>>(row, col, ew, bcur, ebuf2, E, nbuck);
    scatter_phase2_kernel<<<nbuck, 256, 0, stream>>>(ebuf2, row_start, cursor, ebuf, N);

    convw_kernel<<<dim3(64, 3), 256, 0, stream>>>(W0, W1, W2, Wt0, Wt1, Wt2);

    int gblocks = (N + 63) / 64;

    // spmm grid: 8 blocks/CU (32 waves/CU), contiguous row runs per wave
    const int SPMM_BLOCKS = 2048;
    const int totalWaves = SPMM_BLOCKS * 4;
    const int K = (N + totalWaves - 1) / totalWaves;

    // ---- layer 0 ----
    gemm_mfma_f32_kernel<<<gblocks, 256, 0, stream>>>(x, Wt0, b0, H, N);
    spmm_bf16_kernel<<<SPMM_BLOCKS, 256, 0, stream>>>(H, row_start, ebuf, nullptr, Sb, 1, N, K);
    hipMemsetAsync(sums, 0, 256 * 4, stream);
    bn_stats_bf16_kernel<<<256, 256, 0, stream>>>(Sb, sums, N);

    // ---- layer 1 ----
    gemm_mfma_bf16_kernel<<<gblocks, 256, 0, stream>>>(Sb, Wt1, b1, sums, g0, be0, H, N);
    spmm_bf16_kernel<<<SPMM_BLOCKS, 256, 0, stream>>>(H, row_start, ebuf, nullptr, Sb, 1, N, K);
    hipMemsetAsync(sums, 0, 256 * 4, stream);
    bn_stats_bf16_kernel<<<256, 256, 0, stream>>>(Sb, sums, N);

    // ---- layer 2 (final: fp32 out, no BN after) ----
    gemm_mfma_bf16_kernel<<<gblocks, 256, 0, stream>>>(Sb, Wt2, b2, sums, g1, be1, H, N);
    spmm_bf16_kernel<<<SPMM_BLOCKS, 256, 0, stream>>>(H, row_start, ebuf, out, nullptr, 0, N, K);
}